// Round 5
// baseline (586.458 us; speedup 1.0000x reference)
//
#include <hip/hip_runtime.h>

// N=1024, F_NODE=64, F_EDGE=32, F_IN=160.
// out[a,j] = sum_b gated(a,b,j);  gated = relu(Hp)*sigmoid(Ha)
// Hp[a,b,j] = A[a,b]*(H[a]·W[0:64,j] + H[b]·W[64:128,j] + E[a,b]·W[128:160,j]) + bias[j]
// A in {0,1}: A=0 pairs contribute g0[j]=relu(bias)*sigmoid(bias) (constant).
//
// R13 (this round): STREAM E instead of gathering compacted rows.
//  - R11/R12 showed the loop is not latency-bound (depth-2@occ3 already
//    covers ~900cy; depth-4@occ2 regressed). Remaining suspect: gather
//    THROUGHPUT -- 16-distinct-rows-per-instr gather over a 50%-dense row
//    list runs ~1.3-2 TB/s effective. Streaming all 1024 rows per block
//    is 2x bytes at ~6 TB/s stream BW: ~22us vs ~50us.
//  - A=0 rows masked by multiplying the gate with A[a,b] (exact 0.0/1.0)
//    read broadcast from a 4KB LDS copy; (N-c1)*g0 constant path kept.
//  - Deletes: compaction scan, lidx, padding, tail predicate. All 16
//    sub-chunks full + uniform -> perfect CU load balance.
//  - Depth-2 register pipeline, ALL buffer indices literal (rule #20),
//    occ 3 (__launch_bounds__(256,3)), setprio kept.
#define NN 1024
#define FN 64
#define FE 32
#define FIN 160

typedef __bf16 bf16x8 __attribute__((ext_vector_type(8)));
typedef short  short8 __attribute__((ext_vector_type(8)));
typedef float  f32x4  __attribute__((ext_vector_type(4)));

static __device__ __forceinline__ unsigned short f2b(float x){
    unsigned int u = __float_as_uint(x);
    unsigned int r = (u + 0x7fffu + ((u >> 16) & 1u)) >> 16;
    return (unsigned short)r;
}

static __device__ __forceinline__ float fast_sigmoid(float y){
    return __builtin_amdgcn_rcpf(1.0f + __expf(-y));
}

static __device__ __forceinline__ bf16x8 ldfrag(const unsigned short* p){
    return __builtin_bit_cast(bf16x8, *(const short8*)(p));
}

// pack two f32 -> (bf16 lo, bf16 hi) by truncation: one v_perm_b32
static __device__ __forceinline__ unsigned packtrunc(float lo, float hi){
    return __builtin_amdgcn_perm(__float_as_uint(hi), __float_as_uint(lo), 0x07060302u);
}

// blocks 0..63: H f32 -> Hb bf16 (1024x64); block 64/65: W/Wa -> Wt[j][k] bf16
__global__ void prep(const float* __restrict__ H, const float* __restrict__ W,
                     const float* __restrict__ Wa,
                     unsigned short* __restrict__ Hb,
                     unsigned short* __restrict__ WtE,
                     unsigned short* __restrict__ WtA){
    int bid = blockIdx.x, tid = threadIdx.x;
    if (bid < 64){
        int i = (bid*256 + tid)*4;
        float4 v = *(const float4*)(H + i);
        ushort4 o;
        o.x = f2b(v.x); o.y = f2b(v.y); o.z = f2b(v.z); o.w = f2b(v.w);
        *(ushort4*)(Hb + i) = o;
    } else {
        const float* src = (bid == 64) ? W : Wa;
        unsigned short* dst = (bid == 64) ? WtE : WtA;
        for (int idx = tid; idx < FIN*FN; idx += 256){
            int k = idx >> 6, j = idx & 63;
            dst[j*FIN + k] = f2b(src[idx]);
        }
    }
}

// One block per row a. Stream all 1024 b-rows of E[a] (16 sub-chunks of 64),
// mask the gate with A[a,b] from LDS, write out[a,:] directly including the
// (N-c1)*g0 constant term.
// 4 waves, wave=(half<<1)|mh: half -> j-tiles {2half,2half+1}, mh -> 32-row
// half of each 64-row sub-chunk.
// mfma_f32_16x16x32_bf16: A[m=lane&15][k=quad*8+i], B[k][n=lane&15],
// D: col=lane&15, row=quad*4+reg  [measured m89/m91].
__global__ __launch_bounds__(256, 3) void mga_fused(
    const float* __restrict__ A,
    const float* __restrict__ E,
    const unsigned short* __restrict__ Hb,
    const unsigned short* __restrict__ WtE, const unsigned short* __restrict__ WtA,
    const float* __restrict__ bias, float* __restrict__ out)
{
    int a    = blockIdx.x;
    int tid  = threadIdx.x;
    int wave = tid >> 6, lane = tid & 63;
    int col  = lane & 15, quad = lane >> 4;
    int half = wave >> 1, mh = wave & 1;

    __shared__ float amask[NN];            // A row as f32 (values are 0.0/1.0)
    __shared__ float red[16*FN];
    __shared__ int wsum[4];

    // ---- issue A-row load first: latency hides under B-frags + init MFMAs
    int b0 = wave*256 + lane*4;
    float4 av = *(const float4*)(A + (size_t)a*NN + b0);

    // Held B-frags: k-segs {64..96,96..128,128..160} x 2 j-tiles x 2 mats
    bf16x8 Bw[2][3], Ba[2][3];
    #pragma unroll
    for (int tl = 0; tl < 2; tl++){
        int n = (2*half + tl)*16 + col;
        #pragma unroll
        for (int sg = 0; sg < 3; sg++){
            Bw[tl][sg] = ldfrag(WtE + n*FIN + (sg+2)*32 + quad*8);
            Ba[tl][sg] = ldfrag(WtA + n*FIN + (sg+2)*32 + quad*8);
        }
    }

    // Upfront c-init = bias[j] + H[a]·W[0:64,j] via broadcast-A MFMAs
    bf16x8 ha0 = ldfrag(Hb + a*FN + quad*8);
    bf16x8 ha1 = ldfrag(Hb + a*FN + 32 + quad*8);
    f32x4 cw[2], ca[2];
    float acc[2] = {0.f, 0.f};
    #pragma unroll
    for (int tl = 0; tl < 2; tl++){
        int n = (2*half + tl)*16 + col;
        float bj = bias[n];
        f32x4 cb = {bj, bj, bj, bj};
        bf16x8 w0 = ldfrag(WtE + n*FIN + quad*8);
        bf16x8 w1 = ldfrag(WtE + n*FIN + 32 + quad*8);
        cw[tl] = __builtin_amdgcn_mfma_f32_16x16x32_bf16(ha1, w1,
                 __builtin_amdgcn_mfma_f32_16x16x32_bf16(ha0, w0, cb, 0,0,0), 0,0,0);
        w0 = ldfrag(WtA + n*FIN + quad*8);
        w1 = ldfrag(WtA + n*FIN + 32 + quad*8);
        ca[tl] = __builtin_amdgcn_mfma_f32_16x16x32_bf16(ha1, w1,
                 __builtin_amdgcn_mfma_f32_16x16x32_bf16(ha0, w0, cb, 0,0,0), 0,0,0);
    }

    // ---- publish A row to LDS + count nonzeros (no ordering needed)
    *(float4*)(amask + b0) = av;
    int m = 0;
    m += (av.x != 0.f) ? 1 : 0;
    m += (av.y != 0.f) ? 1 : 0;
    m += (av.z != 0.f) ? 1 : 0;
    m += (av.w != 0.f) ? 1 : 0;
    #pragma unroll
    for (int d = 1; d < 64; d <<= 1) m += __shfl_xor(m, d, 64);
    if (lane == 0) wsum[wave] = m;
    __syncthreads();                        // amask + wsum visible
    int c1 = wsum[0] + wsum[1] + wsum[2] + wsum[3];

    // In-flight data for 2 x 64-row sub-chunks x 2 m-tiles (register path).
    // ALL indices into these arrays are compile-time constants (rule #20).
    float4 e0[2][2], e1[2][2]; bf16x8 h0[2][2], h1[2][2];

    // su = sub-chunk index 0..15; rows are LINEAR (streaming, coalesced)
    auto loadsub = [&](int su, int sub){
        #pragma unroll
        for (int mt = 0; mt < 2; mt++){
            int r = su*64 + mh*32 + mt*16 + col;
            const float* ep = E + ((size_t)a*NN + r)*FE + quad*8;
            e0[sub][mt] = *(const float4*)(ep);
            e1[sub][mt] = *(const float4*)(ep + 4);
            h0[sub][mt] = ldfrag(Hb + r*FN + quad*8);
            h1[sub][mt] = ldfrag(Hb + r*FN + 32 + quad*8);
        }
    };

    auto compsub = [&](int su, int sub){
        #pragma unroll
        for (int mt = 0; mt < 2; mt++){
            // gate masks for this fragment's 4 output rows (broadcast reads)
            float am[4];
            #pragma unroll
            for (int r = 0; r < 4; r++)
                am[r] = amask[su*64 + mh*32 + mt*16 + quad*4 + r];
            int4 pk;
            pk.x = (int)packtrunc(e0[sub][mt].x, e0[sub][mt].y);
            pk.y = (int)packtrunc(e0[sub][mt].z, e0[sub][mt].w);
            pk.z = (int)packtrunc(e1[sub][mt].x, e1[sub][mt].y);
            pk.w = (int)packtrunc(e1[sub][mt].z, e1[sub][mt].w);
            bf16x8 ef = __builtin_bit_cast(bf16x8, pk);
            #pragma unroll
            for (int tl = 0; tl < 2; tl++){
                __builtin_amdgcn_s_setprio(1);
                f32x4 pw = __builtin_amdgcn_mfma_f32_16x16x32_bf16(ef, Bw[tl][2],
                           __builtin_amdgcn_mfma_f32_16x16x32_bf16(h1[sub][mt], Bw[tl][1],
                           __builtin_amdgcn_mfma_f32_16x16x32_bf16(h0[sub][mt], Bw[tl][0],
                               cw[tl], 0,0,0), 0,0,0), 0,0,0);
                f32x4 pa = __builtin_amdgcn_mfma_f32_16x16x32_bf16(ef, Ba[tl][2],
                           __builtin_amdgcn_mfma_f32_16x16x32_bf16(h1[sub][mt], Ba[tl][1],
                           __builtin_amdgcn_mfma_f32_16x16x32_bf16(h0[sub][mt], Ba[tl][0],
                               ca[tl], 0,0,0), 0,0,0), 0,0,0);
                __builtin_amdgcn_s_setprio(0);
                #pragma unroll
                for (int r = 0; r < 4; r++){
                    float f = fmaxf(pw[r], 0.f) * fast_sigmoid(pa[r]);
                    acc[tl] += am[r] * f;       // am in {0.0, 1.0}: exact
                }
            }
        }
    };

    // ---- depth-2 pipeline over the 16 uniform sub-chunks (static indices)
    loadsub(0, 0);
    loadsub(1, 1);
    for (int i = 0; i < 16; i += 2){
        compsub(i, 0);
        if (i + 2 < 16) loadsub(i + 2, 0);
        compsub(i + 1, 1);
        if (i + 3 < 16) loadsub(i + 3, 1);
    }

    #pragma unroll
    for (int tl = 0; tl < 2; tl++)
        red[(wave*4 + quad)*FN + (2*half + tl)*16 + col] = acc[tl];
    __syncthreads();
    if (tid < FN){
        int rbase = (tid >= 32) ? 8 : 0;   // waves 0,1: j<32; waves 2,3: j>=32
        float sum = 0.f;
        #pragma unroll
        for (int r = 0; r < 8; r++) sum += red[(rbase + r)*FN + tid];
        float bj = bias[tid];
        float g0 = fmaxf(bj, 0.f) * fast_sigmoid(bj);
        out[(size_t)a*FN + tid] = sum + (float)(NN - c1) * g0;
    }
}

extern "C" void kernel_launch(void* const* d_in, const int* in_sizes, int n_in,
                              void* d_out, int out_size, void* d_ws, size_t ws_size,
                              hipStream_t stream) {
    const float* H    = (const float*)d_in[0];
    const float* A    = (const float*)d_in[1];
    const float* E    = (const float*)d_in[2];
    const float* W    = (const float*)d_in[3];
    const float* Wa   = (const float*)d_in[4];
    const float* bias = (const float*)d_in[5];
    float* out = (float*)d_out;

    unsigned short* Hb   = (unsigned short*)d_ws;         // 1024*64 bf16
    unsigned short* WtE  = Hb + NN*FN;                    // 64*160
    unsigned short* WtA  = WtE + FN*FIN;                  // 64*160

    prep     <<<dim3(66), dim3(256), 0, stream>>>(H, W, Wa, Hb, WtE, WtA);
    mga_fused<<<dim3(NN), dim3(256), 0, stream>>>(A, E, Hb, WtE, WtA, bias, out);
}

// Round 6
// 359.966 us; speedup vs baseline: 1.6292x; 1.6292x over previous
//
#include <hip/hip_runtime.h>

// N=1024, F_NODE=64, F_EDGE=32, F_IN=160.
// out[a,j] = sum_b gated(a,b,j);  gated = relu(Hp)*sigmoid(Ha)
// Hp[a,b,j] = A[a,b]*(H[a]·W[0:64,j] + H[b]·W[64:128,j] + E[a,b]·W[128:160,j]) + bias[j]
// A in {0,1}: A=0 pairs contribute g0[j]=relu(bias)*sigmoid(bias) (constant).
//
// R14 (this round): fix R13's register spill; keep the E-stream.
//  - R13 spilled in the hot loop (VGPR cap 168 @ occ-3 vs ~180 live):
//    FETCH 610MB / WRITE 380MB of scratch traffic, 447us. The streaming
//    idea was never cleanly measured.
//  - Shave 32 VGPRs: double-buffer ONLY the E stream (HBM-critical).
//    H rows are linear and L2-hot (Hb = 128KB, read by all CUs, lives in
//    L2 at ~200cy) -> load H fragments inside compsub as transients;
//    latency hides under pack-VALU + 3 waves/SIMD TLP.
//  - am[] mask LDS reads moved AFTER the MFMA chains (shorter live range).
//  - Steady-state live ~150 VGPR < 168 cap: no spill at occ-3.
//  - Unchanged: A-mask-from-LDS (exact 0/1), (N-c1)*g0 constant path,
//    depth-2 static-index pipeline (rule #20), setprio, reduction.
#define NN 1024
#define FN 64
#define FE 32
#define FIN 160

typedef __bf16 bf16x8 __attribute__((ext_vector_type(8)));
typedef short  short8 __attribute__((ext_vector_type(8)));
typedef float  f32x4  __attribute__((ext_vector_type(4)));

static __device__ __forceinline__ unsigned short f2b(float x){
    unsigned int u = __float_as_uint(x);
    unsigned int r = (u + 0x7fffu + ((u >> 16) & 1u)) >> 16;
    return (unsigned short)r;
}

static __device__ __forceinline__ float fast_sigmoid(float y){
    return __builtin_amdgcn_rcpf(1.0f + __expf(-y));
}

static __device__ __forceinline__ bf16x8 ldfrag(const unsigned short* p){
    return __builtin_bit_cast(bf16x8, *(const short8*)(p));
}

// pack two f32 -> (bf16 lo, bf16 hi) by truncation: one v_perm_b32
static __device__ __forceinline__ unsigned packtrunc(float lo, float hi){
    return __builtin_amdgcn_perm(__float_as_uint(hi), __float_as_uint(lo), 0x07060302u);
}

// blocks 0..63: H f32 -> Hb bf16 (1024x64); block 64/65: W/Wa -> Wt[j][k] bf16
__global__ void prep(const float* __restrict__ H, const float* __restrict__ W,
                     const float* __restrict__ Wa,
                     unsigned short* __restrict__ Hb,
                     unsigned short* __restrict__ WtE,
                     unsigned short* __restrict__ WtA){
    int bid = blockIdx.x, tid = threadIdx.x;
    if (bid < 64){
        int i = (bid*256 + tid)*4;
        float4 v = *(const float4*)(H + i);
        ushort4 o;
        o.x = f2b(v.x); o.y = f2b(v.y); o.z = f2b(v.z); o.w = f2b(v.w);
        *(ushort4*)(Hb + i) = o;
    } else {
        const float* src = (bid == 64) ? W : Wa;
        unsigned short* dst = (bid == 64) ? WtE : WtA;
        for (int idx = tid; idx < FIN*FN; idx += 256){
            int k = idx >> 6, j = idx & 63;
            dst[j*FIN + k] = f2b(src[idx]);
        }
    }
}

// One block per row a. Stream all 1024 b-rows of E[a] (16 sub-chunks of 64),
// mask the gate with A[a,b] from LDS, write out[a,:] directly including the
// (N-c1)*g0 constant term.
// 4 waves, wave=(half<<1)|mh: half -> j-tiles {2half,2half+1}, mh -> 32-row
// half of each 64-row sub-chunk.
// mfma_f32_16x16x32_bf16: A[m=lane&15][k=quad*8+i], B[k][n=lane&15],
// D: col=lane&15, row=quad*4+reg  [measured m89/m91].
__global__ __launch_bounds__(256, 3) void mga_fused(
    const float* __restrict__ A,
    const float* __restrict__ E,
    const unsigned short* __restrict__ Hb,
    const unsigned short* __restrict__ WtE, const unsigned short* __restrict__ WtA,
    const float* __restrict__ bias, float* __restrict__ out)
{
    int a    = blockIdx.x;
    int tid  = threadIdx.x;
    int wave = tid >> 6, lane = tid & 63;
    int col  = lane & 15, quad = lane >> 4;
    int half = wave >> 1, mh = wave & 1;

    __shared__ float amask[NN];            // A row as f32 (values are 0.0/1.0)
    __shared__ float red[16*FN];
    __shared__ int wsum[4];

    // ---- issue A-row load first: latency hides under B-frags + init MFMAs
    int b0 = wave*256 + lane*4;
    float4 av = *(const float4*)(A + (size_t)a*NN + b0);

    // Held B-frags: k-segs {64..96,96..128,128..160} x 2 j-tiles x 2 mats
    bf16x8 Bw[2][3], Ba[2][3];
    #pragma unroll
    for (int tl = 0; tl < 2; tl++){
        int n = (2*half + tl)*16 + col;
        #pragma unroll
        for (int sg = 0; sg < 3; sg++){
            Bw[tl][sg] = ldfrag(WtE + n*FIN + (sg+2)*32 + quad*8);
            Ba[tl][sg] = ldfrag(WtA + n*FIN + (sg+2)*32 + quad*8);
        }
    }

    // Upfront c-init = bias[j] + H[a]·W[0:64,j] via broadcast-A MFMAs
    bf16x8 ha0 = ldfrag(Hb + a*FN + quad*8);
    bf16x8 ha1 = ldfrag(Hb + a*FN + 32 + quad*8);
    f32x4 cw[2], ca[2];
    float acc[2] = {0.f, 0.f};
    #pragma unroll
    for (int tl = 0; tl < 2; tl++){
        int n = (2*half + tl)*16 + col;
        float bj = bias[n];
        f32x4 cb = {bj, bj, bj, bj};
        bf16x8 w0 = ldfrag(WtE + n*FIN + quad*8);
        bf16x8 w1 = ldfrag(WtE + n*FIN + 32 + quad*8);
        cw[tl] = __builtin_amdgcn_mfma_f32_16x16x32_bf16(ha1, w1,
                 __builtin_amdgcn_mfma_f32_16x16x32_bf16(ha0, w0, cb, 0,0,0), 0,0,0);
        w0 = ldfrag(WtA + n*FIN + quad*8);
        w1 = ldfrag(WtA + n*FIN + 32 + quad*8);
        ca[tl] = __builtin_amdgcn_mfma_f32_16x16x32_bf16(ha1, w1,
                 __builtin_amdgcn_mfma_f32_16x16x32_bf16(ha0, w0, cb, 0,0,0), 0,0,0);
    }

    // ---- publish A row to LDS + count nonzeros (no ordering needed)
    *(float4*)(amask + b0) = av;
    int m = 0;
    m += (av.x != 0.f) ? 1 : 0;
    m += (av.y != 0.f) ? 1 : 0;
    m += (av.z != 0.f) ? 1 : 0;
    m += (av.w != 0.f) ? 1 : 0;
    #pragma unroll
    for (int d = 1; d < 64; d <<= 1) m += __shfl_xor(m, d, 64);
    if (lane == 0) wsum[wave] = m;
    __syncthreads();                        // amask + wsum visible
    int c1 = wsum[0] + wsum[1] + wsum[2] + wsum[3];

    // In-flight buffers: E ONLY (2 subs x 2 mt x 32B/lane = 32 VGPR).
    // H is L2-hot (linear rows, 128KB shared by all blocks) -> loaded as
    // transients inside compsub. ALL buffer indices are literals (rule #20).
    float4 e0[2][2], e1[2][2];

    // su = sub-chunk index 0..15; rows are LINEAR (streaming, coalesced)
    auto loadsub = [&](int su, int sub){
        #pragma unroll
        for (int mt = 0; mt < 2; mt++){
            int r = su*64 + mh*32 + mt*16 + col;
            const float* ep = E + ((size_t)a*NN + r)*FE + quad*8;
            e0[sub][mt] = *(const float4*)(ep);
            e1[sub][mt] = *(const float4*)(ep + 4);
        }
    };

    auto compsub = [&](int su, int sub){
        #pragma unroll
        for (int mt = 0; mt < 2; mt++){
            int r = su*64 + mh*32 + mt*16 + col;
            // L2-hot transient H fragments (issued before pack-VALU; ~200cy
            // hidden under packing + other waves)
            bf16x8 h0 = ldfrag(Hb + r*FN + quad*8);
            bf16x8 h1 = ldfrag(Hb + r*FN + 32 + quad*8);
            int4 pk;
            pk.x = (int)packtrunc(e0[sub][mt].x, e0[sub][mt].y);
            pk.y = (int)packtrunc(e0[sub][mt].z, e0[sub][mt].w);
            pk.z = (int)packtrunc(e1[sub][mt].x, e1[sub][mt].y);
            pk.w = (int)packtrunc(e1[sub][mt].z, e1[sub][mt].w);
            bf16x8 ef = __builtin_bit_cast(bf16x8, pk);
            #pragma unroll
            for (int tl = 0; tl < 2; tl++){
                __builtin_amdgcn_s_setprio(1);
                f32x4 pw = __builtin_amdgcn_mfma_f32_16x16x32_bf16(ef, Bw[tl][2],
                           __builtin_amdgcn_mfma_f32_16x16x32_bf16(h1, Bw[tl][1],
                           __builtin_amdgcn_mfma_f32_16x16x32_bf16(h0, Bw[tl][0],
                               cw[tl], 0,0,0), 0,0,0), 0,0,0);
                f32x4 pa = __builtin_amdgcn_mfma_f32_16x16x32_bf16(ef, Ba[tl][2],
                           __builtin_amdgcn_mfma_f32_16x16x32_bf16(h1, Ba[tl][1],
                           __builtin_amdgcn_mfma_f32_16x16x32_bf16(h0, Ba[tl][0],
                               ca[tl], 0,0,0), 0,0,0), 0,0,0);
                __builtin_amdgcn_s_setprio(0);
                // mask reads AFTER the chains: short live range
                #pragma unroll
                for (int r4 = 0; r4 < 4; r4++){
                    float am = amask[su*64 + mh*32 + mt*16 + quad*4 + r4];
                    float f  = fmaxf(pw[r4], 0.f) * fast_sigmoid(pa[r4]);
                    acc[tl] += am * f;          // am in {0.0, 1.0}: exact
                }
            }
        }
    };

    // ---- depth-2 pipeline over the 16 uniform sub-chunks (static indices)
    loadsub(0, 0);
    loadsub(1, 1);
    for (int i = 0; i < 16; i += 2){
        compsub(i, 0);
        if (i + 2 < 16) loadsub(i + 2, 0);
        compsub(i + 1, 1);
        if (i + 3 < 16) loadsub(i + 3, 1);
    }

    #pragma unroll
    for (int tl = 0; tl < 2; tl++)
        red[(wave*4 + quad)*FN + (2*half + tl)*16 + col] = acc[tl];
    __syncthreads();
    if (tid < FN){
        int rbase = (tid >= 32) ? 8 : 0;   // waves 0,1: j<32; waves 2,3: j>=32
        float sum = 0.f;
        #pragma unroll
        for (int r = 0; r < 8; r++) sum += red[(rbase + r)*FN + tid];
        float bj = bias[tid];
        float g0 = fmaxf(bj, 0.f) * fast_sigmoid(bj);
        out[(size_t)a*FN + tid] = sum + (float)(NN - c1) * g0;
    }
}

extern "C" void kernel_launch(void* const* d_in, const int* in_sizes, int n_in,
                              void* d_out, int out_size, void* d_ws, size_t ws_size,
                              hipStream_t stream) {
    const float* H    = (const float*)d_in[0];
    const float* A    = (const float*)d_in[1];
    const float* E    = (const float*)d_in[2];
    const float* W    = (const float*)d_in[3];
    const float* Wa   = (const float*)d_in[4];
    const float* bias = (const float*)d_in[5];
    float* out = (float*)d_out;

    unsigned short* Hb   = (unsigned short*)d_ws;         // 1024*64 bf16
    unsigned short* WtE  = Hb + NN*FN;                    // 64*160
    unsigned short* WtA  = WtE + FN*FIN;                  // 64*160

    prep     <<<dim3(66), dim3(256), 0, stream>>>(H, W, Wa, Hb, WtE, WtA);
    mga_fused<<<dim3(NN), dim3(256), 0, stream>>>(A, E, Hb, WtE, WtA, bias, out);
}